// Round 11
// baseline (470.816 us; speedup 1.0000x reference)
//
#include <hip/hip_runtime.h>
#include <hip/hip_bf16.h>
#include <stdint.h>

#define B_ 4
#define T_ 2048
#define C_ 1024
#define NH_ 16
#define HS_ 64

using bf16 = __hip_bfloat16;
typedef __bf16 bf16x8 __attribute__((ext_vector_type(8)));
typedef float f32x4 __attribute__((ext_vector_type(4)));
typedef short short8 __attribute__((ext_vector_type(8)));

__device__ __forceinline__ f32x4 mfma16(bf16x8 a, bf16x8 b, f32x4 c) {
    return __builtin_amdgcn_mfma_f32_16x16x32_bf16(a, b, c, 0, 0, 0);
}

__device__ __forceinline__ float fexp2(float x) {
    return __builtin_amdgcn_exp2f(x);   // v_exp_f32: 2^x
}

__device__ __forceinline__ short bf16bits(float f) {
    __bf16 b = (__bf16)f;               // RNE f32->bf16
    return *reinterpret_cast<short*>(&b);
}

// async global->LDS 16B copy; LDS dest is wave-uniform base + lane*16
__device__ __forceinline__ void gload16(const void* g, void* l) {
    __builtin_amdgcn_global_load_lds(
        (const __attribute__((address_space(1))) void*)g,
        (__attribute__((address_space(3))) void*)l, 16, 0, 0);
}

// load 8 contiguous elements as bf16 bit-pattern
__device__ __forceinline__ short8 load8(const bf16* p) { return *(const short8*)p; }
__device__ __forceinline__ short8 load8(const float* p) {
    float4 f0 = *(const float4*)p;
    float4 f1 = *(const float4*)(p + 4);
    short8 r;
    r[0] = bf16bits(f0.x); r[1] = bf16bits(f0.y); r[2] = bf16bits(f0.z); r[3] = bf16bits(f0.w);
    r[4] = bf16bits(f1.x); r[5] = bf16bits(f1.y); r[6] = bf16bits(f1.z); r[7] = bf16bits(f1.w);
    return r;
}

__device__ __forceinline__ void storev(bf16* p, float v) { *p = __float2bfloat16(v); }
__device__ __forceinline__ void storev(float* p, float v) { *p = v; }

// XOR swizzle for 64B-row LDS tiles (4 x 16B chunks per row)
__device__ __forceinline__ int swz64(int row, int bytecol) {
    return row * 64 + ((((bytecol >> 4) ^ row) & 3) << 4) + (bytecol & 15);
}

// ---------------- transpose: out[c][r] = bf16(in[r][c]), 64x64 tiles -------
template <typename InT>
__global__ __launch_bounds__(256) void transpose_kernel(
    const InT* __restrict__ in, bf16* __restrict__ out, int R, int C)
{
    __shared__ short tile[64][80];
    const int t = threadIdx.x;
    const size_t batch = (size_t)blockIdx.z * R * C;
    const int bx = blockIdx.x * 64;
    const int by = blockIdx.y * 64;
    const int r = t >> 3, c8 = (t & 7) * 8;

    *(short8*)&tile[r][c8]      = load8(in + batch + (size_t)(by + r) * C + bx + c8);
    *(short8*)&tile[r + 32][c8] = load8(in + batch + (size_t)(by + r + 32) * C + bx + c8);
    __syncthreads();
    short8 v0, v1;
    #pragma unroll
    for (int i = 0; i < 8; ++i) {
        v0[i] = tile[c8 + i][r];
        v1[i] = tile[c8 + i][r + 32];
    }
    *(short8*)((bf16*)out + (size_t)blockIdx.z * R * C + (size_t)(bx + r) * R + by + c8)      = v0;
    *(short8*)((bf16*)out + (size_t)blockIdx.z * R * C + (size_t)(bx + r + 32) * R + by + c8) = v1;
}

// ---------------- GEMM: out = bf16(A[M,K]) @ B + bias, B given as BT[N,K] --
// MODE 0: out[m*N+n] row-major.  MODE 1: split-head out[((b*NH+h)*T+t)*HS+d]
// Staging: global_load_lds with PRE-SWIZZLED global source chunk
// (chunk_g = (lane&3) ^ (row&3)) so the linear HW write matches swz64 reads.
// f32 A falls back to reg-stage + convert + swz64 write.
template <int MODE, typename AT, typename OutT>
__global__ __launch_bounds__(256) void gemm_bias_kernel(
    const AT* __restrict__ A, const bf16* __restrict__ BT,
    const float* __restrict__ bias, OutT* __restrict__ out,
    int M, int N, int K)
{
    constexpr bool A_BF16 = (sizeof(AT) == 2);
    __shared__ __align__(16) short As[128 * 32];
    __shared__ __align__(16) short Bs[128 * 32];
    const int tid = threadIdx.x;
    const int lane = tid & 63;
    const int w = tid >> 6;
    const int wm = w >> 1, wn = w & 1;        // 2x2 waves, 64x64 each
    const int lg = lane >> 4, lr = lane & 15;
    const int bm = blockIdx.x * 128;
    const int bn = blockIdx.y * 128;

    // gload_lds: wave w covers rows w*16..w*16+15 (lane>>2), chunk lane&3.
    const int grow = w * 16 + (lane >> 2);    // 0..63
    const int gch  = (lane & 3) ^ (grow & 3); // pre-swizzled source chunk
    const bf16* gB0 = BT + (size_t)(bn + grow) * K + gch * 8;
    const AT*   gA0 = A  + (size_t)(bm + grow) * K + gch * 8;
    char* lB0 = (char*)Bs + w * 1024;         // wave-uniform LDS base
    char* lA0 = (char*)As + w * 1024;

    // f32-A reg staging assignment
    const int sr = tid >> 2;                  // staging row 0..63
    const int sc = (tid & 3) * 16;            // staging byte col
    const AT* gA = A + (size_t)(bm + sr) * K + (tid & 3) * 8;

    f32x4 acc[4][4] = {};

    for (int k0 = 0; k0 < K; k0 += 32) {
        __syncthreads();
        gload16(gB0 + k0, lB0);
        gload16(gB0 + (size_t)64 * K + k0, lB0 + 4096);
        if constexpr (A_BF16) {
            gload16(gA0 + k0, lA0);
            gload16(gA0 + (size_t)64 * K + k0, lA0 + 4096);
        } else {
            short8 a0 = load8(gA + k0);
            short8 a1 = load8(gA + (size_t)64 * K + k0);
            *(short8*)((char*)As + swz64(sr, sc))      = a0;
            *(short8*)((char*)As + swz64(sr + 64, sc)) = a1;
        }
        __syncthreads();
        bf16x8 af[4], bfv[4];
        #pragma unroll
        for (int i = 0; i < 4; ++i) {
            af[i]  = *(const bf16x8*)((char*)As + swz64(wm * 64 + i * 16 + lr, lg * 16));
            bfv[i] = *(const bf16x8*)((char*)Bs + swz64(wn * 64 + i * 16 + lr, lg * 16));
        }
        #pragma unroll
        for (int mi = 0; mi < 4; ++mi)
            #pragma unroll
            for (int nj = 0; nj < 4; ++nj)
                acc[mi][nj] = mfma16(af[mi], bfv[nj], acc[mi][nj]);
    }

    #pragma unroll
    for (int mi = 0; mi < 4; ++mi) {
        #pragma unroll
        for (int nj = 0; nj < 4; ++nj) {
            const int n = bn + wn * 64 + nj * 16 + lr;
            const float bv = bias[n];
            #pragma unroll
            for (int r = 0; r < 4; ++r) {
                const int m = bm + wm * 64 + mi * 16 + lg * 4 + r;
                const float val = acc[mi][nj][r] + bv;
                size_t idx;
                if (MODE == 1) {
                    idx = (size_t)((m >> 11) * NH_ + (n >> 6)) * (T_ * HS_)
                        + (size_t)(m & (T_ - 1)) * HS_ + (n & (HS_ - 1));
                } else {
                    idx = (size_t)m * N + n;
                }
                storev(out + idx, val);
            }
        }
    }
}

// ---------------- causal flash attention -----------------------------------
// r10 structure, but V fragments read DIRECTLY from global (L2-resident;
// all bq-blocks of one head land on the same XCD: linear id = bh + 64*bq,
// stride 64 % 8 == 0) and issued at tile top (T14 early-issue).
// LDS 48KB (Ks dbuf 16K + Ps 32K) -> 3 blocks/CU when VGPR <= 85.
// launch_bounds(512,4): do NOT squeeze VGPR (r8: (512,6) -> scratch spill).
__global__ __launch_bounds__(512, 4) void attn_kernel(
    const bf16* __restrict__ Qh, const bf16* __restrict__ Kh,
    const bf16* __restrict__ Vt, bf16* __restrict__ Ob)
{
    __shared__ __align__(16) char Ks[2][8192];   // 64 rows x 128B, chunk-swizzled
    __shared__ __align__(16) char Ps[8][2][2048];

    const int tid  = threadIdx.x;
    const int lane = tid & 63;
    const int w    = tid >> 6;            // 0..7
    const int lg = lane >> 4, lr = lane & 15;
    const int bh = blockIdx.x;            // b*NH + h
    const int bq = blockIdx.y;            // 0..7
    const size_t hb = (size_t)bh * (T_ * HS_);

    const int s_lo = bq * 8 + w;          // 0..63
    const int s_hi = 127 - s_lo;          // 64..127
    const int qbase[2] = { s_lo * 16, s_hi * 16 };
    const int last_t[2] = { s_lo >> 2, s_hi >> 2 };
    const int nt = 32 - 2 * bq;           // tiles staged by this block

    const int swzp = (lr & 7) << 4;       // P-tile row swizzle
    const float SC = 0.125f * 1.44269504088896f;

    // K staging: thread handles row = tid>>3, chunk = tid&7 (16B)
    const int strow = tid >> 3;           // 0..63
    const int stch  = tid & 7;            // 0..7
    const int stdst = strow * 128 + ((stch ^ (strow & 7)) << 4);
    const bf16* gK = Kh + hb + (size_t)strow * HS_ + stch * 8;
    // V direct-from-global base: row lr (d-dim, +d*16), col lg*8 (+j0+kfi*32)
    const bf16* pV = Vt + hb + (size_t)lr * T_ + lg * 8;

    bf16x8 qf[2][2];
    #pragma unroll
    for (int qs = 0; qs < 2; ++qs)
        #pragma unroll
        for (int kfi = 0; kfi < 2; ++kfi)
            qf[qs][kfi] = *(const bf16x8*)(Qh + hb + (size_t)(qbase[qs] + lr) * HS_ + kfi * 32 + lg * 8);

    f32x4 accO[2][4] = {};
    float m_s[2] = {-1e30f, -1e30f};
    float l_s[2] = {0.f, 0.f};
    char* pwq[2] = {&Ps[w][0][0], &Ps[w][1][0]};

    // prologue: stage K tile 0
    uint4 kst = *(const uint4*)(gK);
    *(uint4*)(&Ks[0][stdst]) = kst;
    __syncthreads();

    int c = 0;
    for (int t = 0; t < nt; ++t) {
        const int j0 = t * 64;
        // issue V fragment loads for THIS tile early (consumed in PV below)
        bf16x8 vfr[4][2];
        #pragma unroll
        for (int d = 0; d < 4; ++d)
            #pragma unroll
            for (int kfi = 0; kfi < 2; ++kfi)
                vfr[d][kfi] = *(const bf16x8*)(pV + (size_t)d * (16 * T_) + j0 + kfi * 32);
        // issue next K tile global load early
        if (t + 1 < nt)
            kst = *(const uint4*)(gK + (size_t)(t + 1) * 64 * HS_);

        const char* Kc = &Ks[c][0];
        const bool act[2] = { t <= last_t[0], t <= last_t[1] };

        // ---- K fragments from LDS ----
        bf16x8 kfr[4][2];
        #pragma unroll
        for (int s = 0; s < 4; ++s)
            #pragma unroll
            for (int kfi = 0; kfi < 2; ++kfi)
                kfr[s][kfi] = *(const bf16x8*)(Kc + (s * 16 + lr) * 128 + (((kfi * 4 + lg) ^ (lr & 7)) << 4));

        #pragma unroll
        for (int qs = 0; qs < 2; ++qs) {
            if (!act[qs]) continue;
            // S^T: col=q (lane&15), row=k-within-16 (4*lg+r)
            f32x4 st[4];
            #pragma unroll
            for (int s = 0; s < 4; ++s) {
                f32x4 a = {};
                #pragma unroll
                for (int kfi = 0; kfi < 2; ++kfi)
                    a = mfma16(kfr[s][kfi], qf[qs][kfi], a);
                st[s] = a;
            }
            float p[4][4];
            #pragma unroll
            for (int s = 0; s < 4; ++s)
                #pragma unroll
                for (int r = 0; r < 4; ++r)
                    p[s][r] = st[s][r] * SC;
            if (t == last_t[qs]) {        // diagonal tile: causal mask
                const int q = qbase[qs] + lr;
                #pragma unroll
                for (int s = 0; s < 4; ++s)
                    #pragma unroll
                    for (int r = 0; r < 4; ++r)
                        if (j0 + s * 16 + 4 * lg + r > q) p[s][r] = -1e30f;
            }
            // row max: in-lane tree + 2 cross-group shuffles (row = q = lr)
            float mx0 = fmaxf(fmaxf(p[0][0], p[0][1]), fmaxf(p[0][2], p[0][3]));
            float mx1 = fmaxf(fmaxf(p[1][0], p[1][1]), fmaxf(p[1][2], p[1][3]));
            float mx2 = fmaxf(fmaxf(p[2][0], p[2][1]), fmaxf(p[2][2], p[2][3]));
            float mx3 = fmaxf(fmaxf(p[3][0], p[3][1]), fmaxf(p[3][2], p[3][3]));
            float mx = fmaxf(fmaxf(mx0, mx1), fmaxf(mx2, mx3));
            mx = fmaxf(mx, __shfl_xor(mx, 16));
            mx = fmaxf(mx, __shfl_xor(mx, 32));
            // T13 defer-max: only rescale when max grew past threshold
            if (!__all(mx <= m_s[qs] + 8.0f)) {
                const float mnew = fmaxf(m_s[qs], mx);
                const float sf = fexp2(m_s[qs] - mnew);
                m_s[qs] = mnew;
                l_s[qs] *= sf;
                f32x4 sfv;
                #pragma unroll
                for (int r = 0; r < 4; ++r)
                    sfv[r] = __shfl(sf, 4 * lg + r);
                #pragma unroll
                for (int d = 0; d < 4; ++d)
                    accO[qs][d] *= sfv;
            }
            float rs = 0.f;
            #pragma unroll
            for (int s = 0; s < 4; ++s)
                #pragma unroll
                for (int r = 0; r < 4; ++r) {
                    p[s][r] = fexp2(p[s][r] - m_s[qs]);
                    rs += p[s][r];
                }
            rs += __shfl_xor(rs, 16);
            rs += __shfl_xor(rs, 32);
            l_s[qs] += rs;
            // pack 4 consecutive-k bf16 and write 8B (swizzled)
            #pragma unroll
            for (int s = 0; s < 4; ++s) {
                uint2 pk;
                pk.x = (uint16_t)bf16bits(p[s][0]) | ((uint32_t)(uint16_t)bf16bits(p[s][1]) << 16);
                pk.y = (uint16_t)bf16bits(p[s][2]) | ((uint32_t)(uint16_t)bf16bits(p[s][3]) << 16);
                *(uint2*)(pwq[qs] + ((lr * 128 + s * 32 + lg * 8) ^ swzp)) = pk;
            }
        }
        __builtin_amdgcn_wave_barrier();

        // ---- PV for both qs (V fragments already in registers) ----
        #pragma unroll
        for (int qs = 0; qs < 2; ++qs) {
            if (!act[qs]) continue;
            bf16x8 aP[2];
            #pragma unroll
            for (int kfi = 0; kfi < 2; ++kfi)
                aP[kfi] = *(const bf16x8*)(pwq[qs] + ((lr * 128 + kfi * 64 + lg * 16) ^ swzp));
            #pragma unroll
            for (int d = 0; d < 4; ++d)
                #pragma unroll
                for (int kfi = 0; kfi < 2; ++kfi)
                    accO[qs][d] = mfma16(aP[kfi], vfr[d][kfi], accO[qs][d]);
        }

        // ---- write next K tile's staged regs into other buffer ----
        if (t + 1 < nt)
            *(uint4*)(&Ks[c ^ 1][stdst]) = kst;
        __syncthreads();
        c ^= 1;
    }

    // epilogue: redistribute l (owner lane = 4*lg+r), write Ob[b][t][h][d]
    const int b = bh >> 4, h = bh & 15;
    #pragma unroll
    for (int qs = 0; qs < 2; ++qs) {
        float lsv[4];
        #pragma unroll
        for (int r = 0; r < 4; ++r)
            lsv[r] = __shfl(l_s[qs], 4 * lg + r);
        #pragma unroll
        for (int d = 0; d < 4; ++d)
            #pragma unroll
            for (int r = 0; r < 4; ++r) {
                const int q = qbase[qs] + 4 * lg + r;
                const float o = accO[qs][d][r] / lsv[r];
                Ob[(((size_t)b * T_ + q) * NH_ + h) * HS_ + d * 16 + lr] = __float2bfloat16(o);
            }
    }
}

// ---------------- launch ----------------------------------------------------
extern "C" void kernel_launch(void* const* d_in, const int* in_sizes, int n_in,
                              void* d_out, int out_size, void* d_ws, size_t ws_size,
                              hipStream_t stream)
{
    (void)in_sizes; (void)n_in; (void)out_size; (void)ws_size;
    const float* Xq = (const float*)d_in[0];
    const float* Xk = (const float*)d_in[1];
    const float* Xv = (const float*)d_in[2];
    // d_in[3] = mask: known causal triu(k=1); implemented analytically.
    const float* Wq = (const float*)d_in[4];
    const float* bq = (const float*)d_in[5];
    const float* Wk = (const float*)d_in[6];
    const float* bk = (const float*)d_in[7];
    const float* Wv = (const float*)d_in[8];
    const float* bv = (const float*)d_in[9];
    const float* Wo = (const float*)d_in[10];
    const float* bo = (const float*)d_in[11];

    char* ws = (char*)d_ws;
    bf16* WqT = (bf16*)(ws + ((size_t)0  << 20));  // 2MB each (bf16 transposed)
    bf16* WkT = (bf16*)(ws + ((size_t)2  << 20));
    bf16* WvT = (bf16*)(ws + ((size_t)4  << 20));
    bf16* WoT = (bf16*)(ws + ((size_t)6  << 20));
    bf16* Qh  = (bf16*)(ws + ((size_t)8  << 20));  // 16MB each
    bf16* Kh  = (bf16*)(ws + ((size_t)24 << 20));
    bf16* Vh  = (bf16*)(ws + ((size_t)40 << 20));
    bf16* VtG = (bf16*)(ws + ((size_t)56 << 20));
    bf16* Ob  = (bf16*)(ws + ((size_t)72 << 20));  // ends at 88MB

    dim3 blk(256);
    transpose_kernel<float><<<dim3(16, 16, 1), blk, 0, stream>>>(Wq, WqT, 1024, 1024);
    transpose_kernel<float><<<dim3(16, 16, 1), blk, 0, stream>>>(Wk, WkT, 1024, 1024);
    transpose_kernel<float><<<dim3(16, 16, 1), blk, 0, stream>>>(Wv, WvT, 1024, 1024);
    transpose_kernel<float><<<dim3(16, 16, 1), blk, 0, stream>>>(Wo, WoT, 1024, 1024);

    gemm_bias_kernel<1, float, bf16><<<dim3(64, 8), blk, 0, stream>>>(Xq, WqT, bq, Qh, 8192, 1024, 1024);
    gemm_bias_kernel<1, float, bf16><<<dim3(64, 8), blk, 0, stream>>>(Xk, WkT, bk, Kh, 8192, 1024, 1024);
    gemm_bias_kernel<1, float, bf16><<<dim3(64, 8), blk, 0, stream>>>(Xv, WvT, bv, Vh, 8192, 1024, 1024);

    // per-head V transpose: [bh][t][d] -> [bh][d][t]
    transpose_kernel<bf16><<<dim3(1, 32, B_ * NH_), blk, 0, stream>>>(Vh, VtG, T_, HS_);

    attn_kernel<<<dim3(64, 8), dim3(512), 0, stream>>>(Qh, Kh, VtG, Ob);

    // final projection written as FLOAT32 (reference output dtype)
    gemm_bias_kernel<0, bf16, float><<<dim3(64, 8), blk, 0, stream>>>(Ob, WoT, bo, (float*)d_out, 8192, 1024, 1024);
}

// Round 12
// 210.135 us; speedup vs baseline: 2.2405x; 2.2405x over previous
//
#include <hip/hip_runtime.h>
#include <hip/hip_bf16.h>
#include <stdint.h>

#define B_ 4
#define T_ 2048
#define C_ 1024
#define NH_ 16
#define HS_ 64

using bf16 = __hip_bfloat16;
typedef __bf16 bf16x8 __attribute__((ext_vector_type(8)));
typedef float f32x4 __attribute__((ext_vector_type(4)));
typedef short short8 __attribute__((ext_vector_type(8)));

__device__ __forceinline__ f32x4 mfma16(bf16x8 a, bf16x8 b, f32x4 c) {
    return __builtin_amdgcn_mfma_f32_16x16x32_bf16(a, b, c, 0, 0, 0);
}

__device__ __forceinline__ float fexp2(float x) {
    return __builtin_amdgcn_exp2f(x);   // v_exp_f32: 2^x
}

__device__ __forceinline__ short bf16bits(float f) {
    __bf16 b = (__bf16)f;               // RNE f32->bf16
    return *reinterpret_cast<short*>(&b);
}

// async global->LDS 16B copy; LDS dest is wave-uniform base + lane*16
__device__ __forceinline__ void gload16(const void* g, void* l) {
    __builtin_amdgcn_global_load_lds(
        (const __attribute__((address_space(1))) void*)g,
        (__attribute__((address_space(3))) void*)l, 16, 0, 0);
}

// load 8 contiguous elements as bf16 bit-pattern
__device__ __forceinline__ short8 load8(const bf16* p) { return *(const short8*)p; }
__device__ __forceinline__ short8 load8(const float* p) {
    float4 f0 = *(const float4*)p;
    float4 f1 = *(const float4*)(p + 4);
    short8 r;
    r[0] = bf16bits(f0.x); r[1] = bf16bits(f0.y); r[2] = bf16bits(f0.z); r[3] = bf16bits(f0.w);
    r[4] = bf16bits(f1.x); r[5] = bf16bits(f1.y); r[6] = bf16bits(f1.z); r[7] = bf16bits(f1.w);
    return r;
}

__device__ __forceinline__ void storev(bf16* p, float v) { *p = __float2bfloat16(v); }
__device__ __forceinline__ void storev(float* p, float v) { *p = v; }

// XOR swizzle for 64B-row LDS tiles (4 x 16B chunks per row)
__device__ __forceinline__ int swz64(int row, int bytecol) {
    return row * 64 + ((((bytecol >> 4) ^ row) & 3) << 4) + (bytecol & 15);
}

// ---------------- transpose body: out[c][r] = bf16(in[r][c]), 64x64 tiles --
template <typename InT>
__device__ __forceinline__ void transpose_body(
    const InT* __restrict__ in, bf16* __restrict__ out, int R, int C, int zb)
{
    __shared__ short tile[64][80];
    const int t = threadIdx.x;
    const size_t batch = (size_t)zb * R * C;
    const int bx = blockIdx.x * 64;
    const int by = blockIdx.y * 64;
    const int r = t >> 3, c8 = (t & 7) * 8;

    *(short8*)&tile[r][c8]      = load8(in + batch + (size_t)(by + r) * C + bx + c8);
    *(short8*)&tile[r + 32][c8] = load8(in + batch + (size_t)(by + r + 32) * C + bx + c8);
    __syncthreads();
    short8 v0, v1;
    #pragma unroll
    for (int i = 0; i < 8; ++i) {
        v0[i] = tile[c8 + i][r];
        v1[i] = tile[c8 + i][r + 32];
    }
    *(short8*)(out + batch + (size_t)(bx + r) * R + by + c8)      = v0;
    *(short8*)(out + batch + (size_t)(bx + r + 32) * R + by + c8) = v1;
}

// batched per-head V transpose [bh][t][d] -> [bh][d][t]
__global__ __launch_bounds__(256) void transpose_v_kernel(
    const bf16* __restrict__ in, bf16* __restrict__ out)
{
    transpose_body<bf16>(in, out, T_, HS_, blockIdx.z);
}

// all 4 weight transposes in one launch (z selects the weight)
__global__ __launch_bounds__(256) void transpose_w4_kernel(
    const float* __restrict__ Wq, const float* __restrict__ Wk,
    const float* __restrict__ Wv, const float* __restrict__ Wo,
    bf16* __restrict__ WqT, bf16* __restrict__ WkT,
    bf16* __restrict__ WvT, bf16* __restrict__ WoT)
{
    const int z = blockIdx.z;
    const float* in = (z == 0) ? Wq : (z == 1) ? Wk : (z == 2) ? Wv : Wo;
    bf16* out      = (z == 0) ? WqT : (z == 1) ? WkT : (z == 2) ? WvT : WoT;
    transpose_body<float>(in, out, 1024, 1024, 0);
}

// ---------------- GEMM body: out = bf16(A[M,K]) @ B + bias, B as BT[N,K] ---
// MODE 0: out[m*N+n] row-major.  MODE 1: split-head out[((b*NH+h)*T+t)*HS+d]
// B staged via global_load_lds with PRE-SWIZZLED global source chunk
// (chunk_g = (lane&3) ^ (row&3)) so linear HW write matches swz64 reads.
// f32 A: reg-stage + convert + swz64 write.  bf16 A: gload_lds like B.
template <int MODE, typename AT, typename OutT>
__device__ __forceinline__ void gemm_body(
    const AT* __restrict__ A, const bf16* __restrict__ BT,
    const float* __restrict__ bias, OutT* __restrict__ out,
    int M, int N, int K)
{
    constexpr bool A_BF16 = (sizeof(AT) == 2);
    __shared__ __align__(16) short As[128 * 32];
    __shared__ __align__(16) short Bs[128 * 32];
    const int tid = threadIdx.x;
    const int lane = tid & 63;
    const int w = tid >> 6;
    const int wm = w >> 1, wn = w & 1;        // 2x2 waves, 64x64 each
    const int lg = lane >> 4, lr = lane & 15;
    const int bm = blockIdx.x * 128;
    const int bn = blockIdx.y * 128;

    const int grow = w * 16 + (lane >> 2);    // 0..63
    const int gch  = (lane & 3) ^ (grow & 3); // pre-swizzled source chunk
    const bf16* gB0 = BT + (size_t)(bn + grow) * K + gch * 8;
    const AT*   gA0 = A  + (size_t)(bm + grow) * K + gch * 8;
    char* lB0 = (char*)Bs + w * 1024;         // wave-uniform LDS base
    char* lA0 = (char*)As + w * 1024;

    const int sr = tid >> 2;                  // f32-A staging row 0..63
    const int sc = (tid & 3) * 16;            // staging byte col
    const AT* gA = A + (size_t)(bm + sr) * K + (tid & 3) * 8;

    f32x4 acc[4][4] = {};

    for (int k0 = 0; k0 < K; k0 += 32) {
        __syncthreads();
        gload16(gB0 + k0, lB0);
        gload16(gB0 + (size_t)64 * K + k0, lB0 + 4096);
        if constexpr (A_BF16) {
            gload16(gA0 + k0, lA0);
            gload16(gA0 + (size_t)64 * K + k0, lA0 + 4096);
        } else {
            short8 a0 = load8(gA + k0);
            short8 a1 = load8(gA + (size_t)64 * K + k0);
            *(short8*)((char*)As + swz64(sr, sc))      = a0;
            *(short8*)((char*)As + swz64(sr + 64, sc)) = a1;
        }
        __syncthreads();
        bf16x8 af[4], bfv[4];
        #pragma unroll
        for (int i = 0; i < 4; ++i) {
            af[i]  = *(const bf16x8*)((char*)As + swz64(wm * 64 + i * 16 + lr, lg * 16));
            bfv[i] = *(const bf16x8*)((char*)Bs + swz64(wn * 64 + i * 16 + lr, lg * 16));
        }
        #pragma unroll
        for (int mi = 0; mi < 4; ++mi)
            #pragma unroll
            for (int nj = 0; nj < 4; ++nj)
                acc[mi][nj] = mfma16(af[mi], bfv[nj], acc[mi][nj]);
    }

    #pragma unroll
    for (int mi = 0; mi < 4; ++mi) {
        #pragma unroll
        for (int nj = 0; nj < 4; ++nj) {
            const int n = bn + wn * 64 + nj * 16 + lr;
            const float bv = bias[n];
            #pragma unroll
            for (int r = 0; r < 4; ++r) {
                const int m = bm + wm * 64 + mi * 16 + lg * 4 + r;
                const float val = acc[mi][nj][r] + bv;
                size_t idx;
                if (MODE == 1) {
                    idx = (size_t)((m >> 11) * NH_ + (n >> 6)) * (T_ * HS_)
                        + (size_t)(m & (T_ - 1)) * HS_ + (n & (HS_ - 1));
                } else {
                    idx = (size_t)m * N + n;
                }
                storev(out + idx, val);
            }
        }
    }
}

// fused QKV projection: blockIdx.z selects {q,k,v}
__global__ __launch_bounds__(256) void gemm_qkv_kernel(
    const float* __restrict__ Xq, const float* __restrict__ Xk, const float* __restrict__ Xv,
    const bf16* __restrict__ WqT, const bf16* __restrict__ WkT, const bf16* __restrict__ WvT,
    const float* __restrict__ bq, const float* __restrict__ bk, const float* __restrict__ bv,
    bf16* __restrict__ Qh, bf16* __restrict__ Kh, bf16* __restrict__ Vh)
{
    const int z = blockIdx.z;
    const float* A  = (z == 0) ? Xq : (z == 1) ? Xk : Xv;
    const bf16* BT  = (z == 0) ? WqT : (z == 1) ? WkT : WvT;
    const float* bs = (z == 0) ? bq : (z == 1) ? bk : bv;
    bf16* out       = (z == 0) ? Qh : (z == 1) ? Kh : Vh;
    gemm_body<1, float, bf16>(A, BT, bs, out, 8192, 1024, 1024);
}

// final projection (bf16 A, f32 out)
__global__ __launch_bounds__(256) void gemm_out_kernel(
    const bf16* __restrict__ A, const bf16* __restrict__ BT,
    const float* __restrict__ bias, float* __restrict__ out)
{
    gemm_body<0, bf16, float>(A, BT, bias, out, 8192, 1024, 1024);
}

// ---------------- causal flash attention (r10 structure + softmax trims) ---
// Folded work balance + block-staged double-buffered K/V in LDS.
// 8 waves/block; wave w owns q-subtiles s_lo=8*bq+w and s_hi=127-s_lo.
// Double P-buffer per wave; 64KB LDS; grid 512 = 2 blocks/CU (grid-capped).
// launch_bounds(512,4): do NOT squeeze VGPR (r8: (512,6) -> scratch spill).
// V stays LDS-staged (r11: V-from-global thrashed L2 -> 414MB HBM fetch).
// Trims: (a) in-lane defer-max early-out (skips 2 shfl_xor max-reduces);
//        (b) per-lane partial l, reduced once in epilogue (skips 2 shfl_xor
//            sum-reduces per qs per tile).
__global__ __launch_bounds__(512, 4) void attn_kernel(
    const bf16* __restrict__ Qh, const bf16* __restrict__ Kh,
    const bf16* __restrict__ Vt, bf16* __restrict__ Ob)
{
    __shared__ __align__(16) char Ks[2][8192];   // 64 rows x 128B, chunk-swizzled
    __shared__ __align__(16) char Vs[2][8192];
    __shared__ __align__(16) char Ps[8][2][2048];

    const int tid  = threadIdx.x;
    const int lane = tid & 63;
    const int w    = tid >> 6;            // 0..7
    const int lg = lane >> 4, lr = lane & 15;
    const int bh = blockIdx.x;            // b*NH + h
    const int bq = blockIdx.y;            // 0..7
    const size_t hb = (size_t)bh * (T_ * HS_);

    const int s_lo = bq * 8 + w;          // 0..63
    const int s_hi = 127 - s_lo;          // 64..127
    const int qbase[2] = { s_lo * 16, s_hi * 16 };
    const int last_t[2] = { s_lo >> 2, s_hi >> 2 };
    const int nt = 32 - 2 * bq;           // tiles staged by this block

    const int swzp = (lr & 7) << 4;       // P-tile row swizzle
    const float SC = 0.125f * 1.44269504088896f;

    // staging assignment: thread handles row = tid>>3, chunk = tid&7 (16B)
    const int strow = tid >> 3;           // 0..63
    const int stch  = tid & 7;            // 0..7
    const int stdst = strow * 128 + ((stch ^ (strow & 7)) << 4);
    const bf16* gK = Kh + hb + (size_t)strow * HS_ + stch * 8;
    const bf16* gV = Vt + hb + (size_t)strow * T_  + stch * 8;

    bf16x8 qf[2][2];
    #pragma unroll
    for (int qs = 0; qs < 2; ++qs)
        #pragma unroll
        for (int kfi = 0; kfi < 2; ++kfi)
            qf[qs][kfi] = *(const bf16x8*)(Qh + hb + (size_t)(qbase[qs] + lr) * HS_ + kfi * 32 + lg * 8);

    f32x4 accO[2][4] = {};
    float m_s[2] = {-1e30f, -1e30f};
    float l_s[2] = {0.f, 0.f};            // per-lane PARTIAL sums (trim b)
    char* pwq[2] = {&Ps[w][0][0], &Ps[w][1][0]};

    // prologue: stage tile 0
    uint4 kst = *(const uint4*)(gK);
    uint4 vst = *(const uint4*)(gV);
    *(uint4*)(&Ks[0][stdst]) = kst;
    *(uint4*)(&Vs[0][stdst]) = vst;
    __syncthreads();

    int c = 0;
    for (int t = 0; t < nt; ++t) {
        // issue next-tile global loads early (latency hides under compute)
        if (t + 1 < nt) {
            kst = *(const uint4*)(gK + (size_t)(t + 1) * 64 * HS_);
            vst = *(const uint4*)(gV + (t + 1) * 64);
        }
        const int j0 = t * 64;
        const char* Kc = &Ks[c][0];
        const char* Vc = &Vs[c][0];
        const bool act[2] = { t <= last_t[0], t <= last_t[1] };

        // ---- K fragments from LDS ----
        bf16x8 kfr[4][2];
        #pragma unroll
        for (int s = 0; s < 4; ++s)
            #pragma unroll
            for (int kfi = 0; kfi < 2; ++kfi)
                kfr[s][kfi] = *(const bf16x8*)(Kc + (s * 16 + lr) * 128 + (((kfi * 4 + lg) ^ (lr & 7)) << 4));

        #pragma unroll
        for (int qs = 0; qs < 2; ++qs) {
            if (!act[qs]) continue;
            // S^T: col=q (lane&15), row=k-within-16 (4*lg+r)
            f32x4 st[4];
            #pragma unroll
            for (int s = 0; s < 4; ++s) {
                f32x4 a = {};
                #pragma unroll
                for (int kfi = 0; kfi < 2; ++kfi)
                    a = mfma16(kfr[s][kfi], qf[qs][kfi], a);
                st[s] = a;
            }
            float p[4][4];
            #pragma unroll
            for (int s = 0; s < 4; ++s)
                #pragma unroll
                for (int r = 0; r < 4; ++r)
                    p[s][r] = st[s][r] * SC;
            if (t == last_t[qs]) {        // diagonal tile: causal mask
                const int q = qbase[qs] + lr;
                #pragma unroll
                for (int s = 0; s < 4; ++s)
                    #pragma unroll
                    for (int r = 0; r < 4; ++r)
                        if (j0 + s * 16 + 4 * lg + r > q) p[s][r] = -1e30f;
            }
            // in-lane max of this lane's 16 values
            float mx0 = fmaxf(fmaxf(p[0][0], p[0][1]), fmaxf(p[0][2], p[0][3]));
            float mx1 = fmaxf(fmaxf(p[1][0], p[1][1]), fmaxf(p[1][2], p[1][3]));
            float mx2 = fmaxf(fmaxf(p[2][0], p[2][1]), fmaxf(p[2][2], p[2][3]));
            float mx3 = fmaxf(fmaxf(p[3][0], p[3][1]), fmaxf(p[3][2], p[3][3]));
            float mxin = fmaxf(fmaxf(mx0, mx1), fmaxf(mx2, mx3));
            // (a) defer-max early-out: cross-lane reduce ONLY when needed
            if (!__all(mxin <= m_s[qs] + 8.0f)) {
                float mx = mxin;
                mx = fmaxf(mx, __shfl_xor(mx, 16));
                mx = fmaxf(mx, __shfl_xor(mx, 32));
                const float mnew = fmaxf(m_s[qs], mx);
                const float sf = fexp2(m_s[qs] - mnew);
                m_s[qs] = mnew;
                l_s[qs] *= sf;
                f32x4 sfv;
                #pragma unroll
                for (int r = 0; r < 4; ++r)
                    sfv[r] = __shfl(sf, 4 * lg + r);
                #pragma unroll
                for (int d = 0; d < 4; ++d)
                    accO[qs][d] *= sfv;
            }
            float rs = 0.f;
            #pragma unroll
            for (int s = 0; s < 4; ++s)
                #pragma unroll
                for (int r = 0; r < 4; ++r) {
                    p[s][r] = fexp2(p[s][r] - m_s[qs]);
                    rs += p[s][r];
                }
            l_s[qs] += rs;                // (b) partial only; no shuffles
            // pack 4 consecutive-k bf16 and write 8B (swizzled)
            #pragma unroll
            for (int s = 0; s < 4; ++s) {
                uint2 pk;
                pk.x = (uint16_t)bf16bits(p[s][0]) | ((uint32_t)(uint16_t)bf16bits(p[s][1]) << 16);
                pk.y = (uint16_t)bf16bits(p[s][2]) | ((uint32_t)(uint16_t)bf16bits(p[s][3]) << 16);
                *(uint2*)(pwq[qs] + ((lr * 128 + s * 32 + lg * 8) ^ swzp)) = pk;
            }
        }
        __builtin_amdgcn_wave_barrier();

        // ---- V fragments from LDS (once per tile), then PV for both qs ----
        bf16x8 vfr[4][2];
        #pragma unroll
        for (int d = 0; d < 4; ++d)
            #pragma unroll
            for (int kfi = 0; kfi < 2; ++kfi)
                vfr[d][kfi] = *(const bf16x8*)(Vc + (d * 16 + lr) * 128 + (((kfi * 4 + lg) ^ (lr & 7)) << 4));

        #pragma unroll
        for (int qs = 0; qs < 2; ++qs) {
            if (!act[qs]) continue;
            bf16x8 aP[2];
            #pragma unroll
            for (int kfi = 0; kfi < 2; ++kfi)
                aP[kfi] = *(const bf16x8*)(pwq[qs] + ((lr * 128 + kfi * 64 + lg * 16) ^ swzp));
            #pragma unroll
            for (int d = 0; d < 4; ++d)
                #pragma unroll
                for (int kfi = 0; kfi < 2; ++kfi)
                    accO[qs][d] = mfma16(aP[kfi], vfr[d][kfi], accO[qs][d]);
        }

        // ---- write next tile's staged regs into other buffer ----
        if (t + 1 < nt) {
            *(uint4*)(&Ks[c ^ 1][stdst]) = kst;
            *(uint4*)(&Vs[c ^ 1][stdst]) = vst;
        }
        __syncthreads();
        c ^= 1;
    }

    // epilogue: total l(q) = sum of 4 owner-lane partials, then write Ob
    const int b = bh >> 4, h = bh & 15;
    #pragma unroll
    for (int qs = 0; qs < 2; ++qs) {
        float lsv[4];
        #pragma unroll
        for (int r = 0; r < 4; ++r) {
            float acc = 0.f;
            #pragma unroll
            for (int g = 0; g < 4; ++g)
                acc += __shfl(l_s[qs], 4 * lg + r + 16 * g);
            lsv[r] = acc;
        }
        #pragma unroll
        for (int d = 0; d < 4; ++d)
            #pragma unroll
            for (int r = 0; r < 4; ++r) {
                const int q = qbase[qs] + 4 * lg + r;
                const float o = accO[qs][d][r] / lsv[r];
                Ob[(((size_t)b * T_ + q) * NH_ + h) * HS_ + d * 16 + lr] = __float2bfloat16(o);
            }
    }
}

// ---------------- launch ----------------------------------------------------
extern "C" void kernel_launch(void* const* d_in, const int* in_sizes, int n_in,
                              void* d_out, int out_size, void* d_ws, size_t ws_size,
                              hipStream_t stream)
{
    (void)in_sizes; (void)n_in; (void)out_size; (void)ws_size;
    const float* Xq = (const float*)d_in[0];
    const float* Xk = (const float*)d_in[1];
    const float* Xv = (const float*)d_in[2];
    // d_in[3] = mask: known causal triu(k=1); implemented analytically.
    const float* Wq = (const float*)d_in[4];
    const float* bq = (const float*)d_in[5];
    const float* Wk = (const float*)d_in[6];
    const float* bk = (const float*)d_in[7];
    const float* Wv = (const float*)d_in[8];
    const float* bv = (const float*)d_in[9];
    const float* Wo = (const float*)d_in[10];
    const float* bo = (const float*)d_in[11];

    char* ws = (char*)d_ws;
    bf16* WqT = (bf16*)(ws + ((size_t)0  << 20));  // 2MB each (bf16 transposed)
    bf16* WkT = (bf16*)(ws + ((size_t)2  << 20));
    bf16* WvT = (bf16*)(ws + ((size_t)4  << 20));
    bf16* WoT = (bf16*)(ws + ((size_t)6  << 20));
    bf16* Qh  = (bf16*)(ws + ((size_t)8  << 20));  // 16MB each
    bf16* Kh  = (bf16*)(ws + ((size_t)24 << 20));
    bf16* Vh  = (bf16*)(ws + ((size_t)40 << 20));
    bf16* VtG = (bf16*)(ws + ((size_t)56 << 20));
    bf16* Ob  = (bf16*)(ws + ((size_t)72 << 20));  // ends at 88MB

    dim3 blk(256);
    transpose_w4_kernel<<<dim3(16, 16, 4), blk, 0, stream>>>(
        Wq, Wk, Wv, Wo, WqT, WkT, WvT, WoT);

    gemm_qkv_kernel<<<dim3(64, 8, 3), blk, 0, stream>>>(
        Xq, Xk, Xv, WqT, WkT, WvT, bq, bk, bv, Qh, Kh, Vh);

    // per-head V transpose: [bh][t][d] -> [bh][d][t]
    transpose_v_kernel<<<dim3(1, 32, B_ * NH_), blk, 0, stream>>>(Vh, VtG);

    attn_kernel<<<dim3(64, 8), dim3(512), 0, stream>>>(Qh, Kh, VtG, Ob);

    // final projection written as FLOAT32 (reference output dtype)
    gemm_out_kernel<<<dim3(64, 8), blk, 0, stream>>>(Ob, WoT, bo, (float*)d_out);
}